// Round 17
// baseline (66.437 us; speedup 1.0000x reference)
//
#include <hip/hip_runtime.h>
#include <math.h>

#define BB 64
#define NN 128
#define DD 128
#define HH 4
#define HD 32
#define FFN_ 128

static constexpr float NEGV  = -9000000000000000.0f;
static constexpr float SLOPE = 0.2f;
static constexpr float SCALE = 0.08838834764831845f; // 1/sqrt(128)
#define NEWTON_ITERS 4

__device__ __forceinline__ float4 f4fma(float s, float4 w, float4 a) {
    a.x += s * w.x; a.y += s * w.y; a.z += s * w.z; a.w += s * w.w; return a;
}

// ---------------- K1: edge attention + softmax + local = att@hidden (+a_ent) ----------------
__global__ __launch_bounds__(512) void k_att_local(
    const float* __restrict__ hidden, const int* __restrict__ adj,
    const float* __restrict__ a0, const float* __restrict__ a1,
    const float* __restrict__ a2, const float* __restrict__ a3,
    const float* __restrict__ wa, const float* __restrict__ ba,
    float* __restrict__ local, float* __restrict__ aent_out)
{
    __shared__ __align__(16) float At[4][132];
    __shared__ __align__(16) float hb[128][128];   // swizzled
    __shared__ __align__(16) float hA[128][132];   // [i*4+r][d], i=0..31 local
    __shared__ __align__(16) float att[32][132];

    const int blk = blockIdx.x;
    const int b  = blk >> 2;
    const int i0 = (blk & 3) * 32;
    const int tid = threadIdx.x;

    {
        int r = tid >> 7, d = tid & 127;
        float v = (r == 0) ? a0[d] : (r == 1) ? a1[d] : (r == 2) ? a2[d] : a3[d];
        At[r][d] = v;
    }
    #pragma unroll
    for (int p = 0; p < 8; ++p) {
        int q = tid + 512 * p;
        int r = q >> 5, cq = q & 31;
        *reinterpret_cast<float4*>(&hb[r][4 * (cq ^ (r >> 2))]) =
            *reinterpret_cast<const float4*>(&hidden[(size_t)b * NN * DD + (size_t)r * DD + 4 * cq]);
    }
    __syncthreads();

    // ---- precompute hA
    #pragma unroll
    for (int p = 0; p < 8; ++p) {
        int idx = tid + 512 * p;
        int i  = idx >> 7;
        int r  = (idx >> 5) & 3;
        int dq = idx & 31;
        float4 hv = *reinterpret_cast<const float4*>(&hb[i0 + i][4 * (dq ^ ((i0 + i) >> 2))]);
        float4 av = *reinterpret_cast<const float4*>(&At[r][4 * dq]);
        *reinterpret_cast<float4*>(&hA[i * 4 + r][4 * dq]) =
            make_float4(hv.x * av.x, hv.y * av.y, hv.z * av.z, hv.w * av.w);
    }
    __syncthreads();

    // ---- Phase A
    {
        const int ig = tid >> 7;
        const int j  = tid & 127;
        const int ib = 8 * ig;
        const int jx = j >> 2;
        int rowk[8];
        bool vk[8];
        #pragma unroll
        for (int k = 0; k < 8; ++k) {
            int a = adj[(size_t)b * NN * NN + (size_t)(i0 + ib + k) * NN + j];
            bool v = (a >= 1 && a <= 4);
            vk[k] = v;
            rowk[k] = (ib + k) * 4 + (v ? (a - 1) : 0);
        }
        float acc[8];
        #pragma unroll
        for (int k = 0; k < 8; ++k) acc[k] = 0.0f;
        #pragma unroll 2
        for (int dq = 0; dq < 32; ++dq) {
            float4 jv = *reinterpret_cast<const float4*>(&hb[j][4 * (dq ^ jx)]);
            #pragma unroll
            for (int k = 0; k < 8; ++k) {
                float4 A = *reinterpret_cast<const float4*>(&hA[rowk[k]][4 * dq]);
                acc[k] += A.x * jv.x + A.y * jv.y + A.z * jv.z + A.w * jv.w;
            }
        }
        #pragma unroll
        for (int k = 0; k < 8; ++k) {
            float e = (acc[k] > 0.0f) ? acc[k] : SLOPE * acc[k];
            att[ib + k][j] = vk[k] ? e : NEGV;
        }
    }
    __syncthreads();

    const int ti2 = tid >> 5;
    const int tl  = tid & 31;

    // ---- Phase B
    #pragma unroll
    for (int rr = 0; rr < 2; ++rr) {
        int row = 2 * ti2 + rr;
        float x0 = att[row][tl], x1 = att[row][tl + 32], x2 = att[row][tl + 64], x3 = att[row][tl + 96];
        float m = fmaxf(fmaxf(x0, x1), fmaxf(x2, x3));
        #pragma unroll
        for (int off = 16; off >= 1; off >>= 1) m = fmaxf(m, __shfl_xor(m, off));
        float q0 = __expf(x0 - m), q1 = __expf(x1 - m), q2 = __expf(x2 - m), q3 = __expf(x3 - m);
        float s = (q0 + q1) + (q2 + q3);
        #pragma unroll
        for (int off = 16; off >= 1; off >>= 1) s += __shfl_xor(s, off);
        float invs = 1.0f / s;
        att[row][tl]      = q0 * invs;
        att[row][tl + 32] = q1 * invs;
        att[row][tl + 64] = q2 * invs;
        att[row][tl + 96] = q3 * invs;
    }

    // ---- Phase C
    const int jg = 4 * tl;
    const int rA = 2 * ti2, rB = 2 * ti2 + 1;
    float4 accA = make_float4(0.0f, 0.0f, 0.0f, 0.0f);
    float4 accB = make_float4(0.0f, 0.0f, 0.0f, 0.0f);
    #pragma unroll 4
    for (int jq = 0; jq < 32; ++jq) {
        int xc = 4 * (tl ^ jq);
        #pragma unroll
        for (int k = 0; k < 4; ++k) {
            int j = 4 * jq + k;
            float aAv = att[rA][j];
            float aBv = att[rB][j];
            float4 h4 = *reinterpret_cast<const float4*>(&hb[j][xc]);
            accA.x += aAv * h4.x; accA.y += aAv * h4.y;
            accA.z += aAv * h4.z; accA.w += aAv * h4.w;
            accB.x += aBv * h4.x; accB.y += aBv * h4.y;
            accB.z += aBv * h4.z; accB.w += aBv * h4.w;
        }
    }
    *reinterpret_cast<float4*>(&local[(size_t)b * NN * DD + (size_t)(i0 + rA) * DD + jg]) = accA;
    *reinterpret_cast<float4*>(&local[(size_t)b * NN * DD + (size_t)(i0 + rB) * DD + jg]) = accB;

    // ---- a_ent
    if (((blk & 3) == 3) && ti2 == 15) {
        float4 wa4 = *reinterpret_cast<const float4*>(&wa[jg]);
        float dp = accB.x * wa4.x + accB.y * wa4.y + accB.z * wa4.z + accB.w * wa4.w;
        #pragma unroll
        for (int off = 16; off >= 1; off >>= 1) dp += __shfl_xor(dp, off, 32);
        if (tl == 0) {
            float z = dp + ba[0];
            float sig = 1.0f / (1.0f + __expf(-z));
            float a = sig + 1.0f;
            if (a == 1.0f) a = 1.00001f;
            aent_out[b] = a;
        }
    }
}

// ---------------- K5: fused QKV (4-row split GEMM) + scores + entmax (all 16 waves) + y ----------------
__global__ __launch_bounds__(1024) void k_qkv_entmax(
    const float* __restrict__ local,
    const float* __restrict__ wq, const float* __restrict__ bq,
    const float* __restrict__ wk, const float* __restrict__ bk,
    const float* __restrict__ wv, const float* __restrict__ bv,
    const float* __restrict__ aent, const int* __restrict__ seq_mask,
    float* __restrict__ y)
{
    __shared__ __align__(16) float lb[128][132];   // local[b]; alpha overlay after GEMM
    __shared__ __align__(16) float wQs[128][36];   // wq slice; Q after overlay
    __shared__ __align__(16) float wKs[128][36];
    __shared__ __align__(16) float wVs[128][36];
    __shared__ __align__(16) float kx[32][132];    // K^T [dh][j]
    __shared__ __align__(16) float vL[128][32];    // V [j][dh]
    __shared__ int maskL[NN];
    __shared__ float aent_sh;

    const int blk = blockIdx.x;
    const int b = blk >> 2, h = blk & 3;
    const int tid = threadIdx.x;

    #pragma unroll
    for (int p = 0; p < 4; ++p) {
        int idx = tid + 1024 * p;
        int r = idx >> 5, cq = idx & 31;
        *reinterpret_cast<float4*>(&lb[r][4 * cq]) =
            *reinterpret_cast<const float4*>(&local[(size_t)b * NN * DD + (size_t)r * DD + 4 * cq]);
    }
    {
        int d = tid >> 3, c4 = 4 * (tid & 7);
        size_t off = (size_t)d * DD + h * HD + c4;
        *reinterpret_cast<float4*>(&wQs[d][c4]) = *reinterpret_cast<const float4*>(&wq[off]);
        *reinterpret_cast<float4*>(&wKs[d][c4]) = *reinterpret_cast<const float4*>(&wk[off]);
        *reinterpret_cast<float4*>(&wVs[d][c4]) = *reinterpret_cast<const float4*>(&wv[off]);
    }
    if (tid < NN) maskL[tid] = seq_mask[b * NN + tid];
    if (tid == 0) aent_sh = aent[b];
    __syncthreads();

    const int t256 = tid & 255;
    const int rp4  = t256 >> 3;
    const int tx4  = t256 & 7;
    const int cg4  = 4 * tx4;
    float4 qa[4];

    if (tid < 256) {
        float4 kb4 = *reinterpret_cast<const float4*>(&bk[h * HD + cg4]);
        float4 vb4 = *reinterpret_cast<const float4*>(&bv[h * HD + cg4]);
        float4 ka0 = kb4, ka1 = kb4, ka2 = kb4, ka3 = kb4;
        float4 va0 = vb4, va1 = vb4, va2 = vb4, va3 = vb4;
        #pragma unroll 4
        for (int kq = 0; kq < 32; ++kq) {
            float4 a0 = *reinterpret_cast<const float4*>(&lb[rp4 +  0][4 * kq]);
            float4 a1 = *reinterpret_cast<const float4*>(&lb[rp4 + 32][4 * kq]);
            float4 a2 = *reinterpret_cast<const float4*>(&lb[rp4 + 64][4 * kq]);
            float4 a3 = *reinterpret_cast<const float4*>(&lb[rp4 + 96][4 * kq]);
            {
                float4 w0 = *reinterpret_cast<const float4*>(&wKs[4 * kq + 0][cg4]);
                float4 w1 = *reinterpret_cast<const float4*>(&wKs[4 * kq + 1][cg4]);
                float4 w2 = *reinterpret_cast<const float4*>(&wKs[4 * kq + 2][cg4]);
                float4 w3 = *reinterpret_cast<const float4*>(&wKs[4 * kq + 3][cg4]);
                ka0 = f4fma(a0.x, w0, ka0); ka0 = f4fma(a0.y, w1, ka0);
                ka0 = f4fma(a0.z, w2, ka0); ka0 = f4fma(a0.w, w3, ka0);
                ka1 = f4fma(a1.x, w0, ka1); ka1 = f4fma(a1.y, w1, ka1);
                ka1 = f4fma(a1.z, w2, ka1); ka1 = f4fma(a1.w, w3, ka1);
                ka2 = f4fma(a2.x, w0, ka2); ka2 = f4fma(a2.y, w1, ka2);
                ka2 = f4fma(a2.z, w2, ka2); ka2 = f4fma(a2.w, w3, ka2);
                ka3 = f4fma(a3.x, w0, ka3); ka3 = f4fma(a3.y, w1, ka3);
                ka3 = f4fma(a3.z, w2, ka3); ka3 = f4fma(a3.w, w3, ka3);
            }
            {
                float4 w0 = *reinterpret_cast<const float4*>(&wVs[4 * kq + 0][cg4]);
                float4 w1 = *reinterpret_cast<const float4*>(&wVs[4 * kq + 1][cg4]);
                float4 w2 = *reinterpret_cast<const float4*>(&wVs[4 * kq + 2][cg4]);
                float4 w3 = *reinterpret_cast<const float4*>(&wVs[4 * kq + 3][cg4]);
                va0 = f4fma(a0.x, w0, va0); va0 = f4fma(a0.y, w1, va0);
                va0 = f4fma(a0.z, w2, va0); va0 = f4fma(a0.w, w3, va0);
                va1 = f4fma(a1.x, w0, va1); va1 = f4fma(a1.y, w1, va1);
                va1 = f4fma(a1.z, w2, va1); va1 = f4fma(a1.w, w3, va1);
                va2 = f4fma(a2.x, w0, va2); va2 = f4fma(a2.y, w1, va2);
                va2 = f4fma(a2.z, w2, va2); va2 = f4fma(a2.w, w3, va2);
                va3 = f4fma(a3.x, w0, va3); va3 = f4fma(a3.y, w1, va3);
                va3 = f4fma(a3.z, w2, va3); va3 = f4fma(a3.w, w3, va3);
            }
        }
        kx[cg4 + 0][rp4 +  0] = ka0.x; kx[cg4 + 1][rp4 +  0] = ka0.y;
        kx[cg4 + 2][rp4 +  0] = ka0.z; kx[cg4 + 3][rp4 +  0] = ka0.w;
        kx[cg4 + 0][rp4 + 32] = ka1.x; kx[cg4 + 1][rp4 + 32] = ka1.y;
        kx[cg4 + 2][rp4 + 32] = ka1.z; kx[cg4 + 3][rp4 + 32] = ka1.w;
        kx[cg4 + 0][rp4 + 64] = ka2.x; kx[cg4 + 1][rp4 + 64] = ka2.y;
        kx[cg4 + 2][rp4 + 64] = ka2.z; kx[cg4 + 3][rp4 + 64] = ka2.w;
        kx[cg4 + 0][rp4 + 96] = ka3.x; kx[cg4 + 1][rp4 + 96] = ka3.y;
        kx[cg4 + 2][rp4 + 96] = ka3.z; kx[cg4 + 3][rp4 + 96] = ka3.w;
        *reinterpret_cast<float4*>(&vL[rp4 +  0][cg4]) = va0;
        *reinterpret_cast<float4*>(&vL[rp4 + 32][cg4]) = va1;
        *reinterpret_cast<float4*>(&vL[rp4 + 64][cg4]) = va2;
        *reinterpret_cast<float4*>(&vL[rp4 + 96][cg4]) = va3;
    } else if (tid < 512) {
        float4 qb4 = *reinterpret_cast<const float4*>(&bq[h * HD + cg4]);
        qa[0] = qb4; qa[1] = qb4; qa[2] = qb4; qa[3] = qb4;
        #pragma unroll 4
        for (int kq = 0; kq < 32; ++kq) {
            float4 a0 = *reinterpret_cast<const float4*>(&lb[rp4 +  0][4 * kq]);
            float4 a1 = *reinterpret_cast<const float4*>(&lb[rp4 + 32][4 * kq]);
            float4 a2 = *reinterpret_cast<const float4*>(&lb[rp4 + 64][4 * kq]);
            float4 a3 = *reinterpret_cast<const float4*>(&lb[rp4 + 96][4 * kq]);
            float4 w0 = *reinterpret_cast<const float4*>(&wQs[4 * kq + 0][cg4]);
            float4 w1 = *reinterpret_cast<const float4*>(&wQs[4 * kq + 1][cg4]);
            float4 w2 = *reinterpret_cast<const float4*>(&wQs[4 * kq + 2][cg4]);
            float4 w3 = *reinterpret_cast<const float4*>(&wQs[4 * kq + 3][cg4]);
            qa[0] = f4fma(a0.x, w0, qa[0]); qa[0] = f4fma(a0.y, w1, qa[0]);
            qa[0] = f4fma(a0.z, w2, qa[0]); qa[0] = f4fma(a0.w, w3, qa[0]);
            qa[1] = f4fma(a1.x, w0, qa[1]); qa[1] = f4fma(a1.y, w1, qa[1]);
            qa[1] = f4fma(a1.z, w2, qa[1]); qa[1] = f4fma(a1.w, w3, qa[1]);
            qa[2] = f4fma(a2.x, w0, qa[2]); qa[2] = f4fma(a2.y, w1, qa[2]);
            qa[2] = f4fma(a2.z, w2, qa[2]); qa[2] = f4fma(a2.w, w3, qa[2]);
            qa[3] = f4fma(a3.x, w0, qa[3]); qa[3] = f4fma(a3.y, w1, qa[3]);
            qa[3] = f4fma(a3.z, w2, qa[3]); qa[3] = f4fma(a3.w, w3, qa[3]);
        }
    }
    __syncthreads();

    if (tid >= 256 && tid < 512) {
        *reinterpret_cast<float4*>(&wQs[rp4 +  0][cg4]) = qa[0];
        *reinterpret_cast<float4*>(&wQs[rp4 + 32][cg4]) = qa[1];
        *reinterpret_cast<float4*>(&wQs[rp4 + 64][cg4]) = qa[2];
        *reinterpret_cast<float4*>(&wQs[rp4 + 96][cg4]) = qa[3];
    }
    __syncthreads();

    // ================= entmax: ALL 1024 threads, 1 row each =================
    {
        const int i   = tid >> 3;
        const int sub = tid & 7;
        const int c0  = 4 * sub;

        const float am1 = aent_sh - 1.0f;
        const float inv = 1.0f / am1;
        const float invm1 = inv - 1.0f;
        const float thi_off = exp2f(-7.0f * am1);
        const float sc = SCALE * am1;
        const float xneg = -1000000000.0f * am1;

        float xv[16];
        #pragma unroll
        for (int s = 0; s < 16; ++s) xv[s] = 0.0f;
        #pragma unroll
        for (int dq = 0; dq < 8; ++dq) {
            float4 q4 = *reinterpret_cast<const float4*>(&wQs[i][4 * dq]);
            #pragma unroll
            for (int kk = 0; kk < 4; ++kk) {
                int dh = 4 * dq + kk;
                float qv = (kk == 0) ? q4.x : (kk == 1) ? q4.y : (kk == 2) ? q4.z : q4.w;
                #pragma unroll
                for (int qq = 0; qq < 4; ++qq) {
                    float4 k4 = *reinterpret_cast<const float4*>(&kx[dh][c0 + 32 * qq]);
                    xv[4 * qq + 0] += qv * k4.x;
                    xv[4 * qq + 1] += qv * k4.y;
                    xv[4 * qq + 2] += qv * k4.z;
                    xv[4 * qq + 3] += qv * k4.w;
                }
            }
        }
        #pragma unroll
        for (int qq = 0; qq < 4; ++qq) {
            int4 m4 = *reinterpret_cast<const int4*>(&maskL[c0 + 32 * qq]);
            xv[4 * qq + 0] = (m4.x == 0) ? xneg : xv[4 * qq + 0] * sc;
            xv[4 * qq + 1] = (m4.y == 0) ? xneg : xv[4 * qq + 1] * sc;
            xv[4 * qq + 2] = (m4.z == 0) ? xneg : xv[4 * qq + 2] * sc;
            xv[4 * qq + 3] = (m4.w == 0) ? xneg : xv[4 * qq + 3] * sc;
        }

        float mx = xv[0];
        #pragma unroll
        for (int s = 1; s < 16; ++s) mx = fmaxf(mx, xv[s]);
        mx = fmaxf(mx, __shfl_xor(mx, 1));
        mx = fmaxf(mx, __shfl_xor(mx, 2));
        mx = fmaxf(mx, __shfl_xor(mx, 4));

        const float hi = mx - thi_off;
        float tau = mx - 1.0f;

        #pragma unroll
        for (int it = 0; it < NEWTON_ITERS; ++it) {
            float ps = 0.0f, ds = 0.0f;
            #pragma unroll
            for (int s = 0; s < 16; ++s) {
                float t = fmaxf(xv[s] - tau, 0.0f);
                float l = __builtin_amdgcn_logf(t);
                float d = __builtin_amdgcn_exp2f(invm1 * l);
                float p = t * d;
                ps += p; ds += d;
            }
            ps += __shfl_xor(ps, 1); ds += __shfl_xor(ds, 1);
            ps += __shfl_xor(ps, 2); ds += __shfl_xor(ds, 2);
            ps += __shfl_xor(ps, 4); ds += __shfl_xor(ds, 4);
            tau = fminf(tau + (ps - 1.0f) * __builtin_amdgcn_rcpf(inv * ds), hi);
        }

        float pm[16];
        float S = 0.0f;
        #pragma unroll
        for (int s = 0; s < 16; ++s) {
            float t = fmaxf(xv[s] - tau, 0.0f);
            float l = __builtin_amdgcn_logf(t);
            float p = t * __builtin_amdgcn_exp2f(invm1 * l);
            pm[s] = p; S += p;
        }
        S += __shfl_xor(S, 1);
        S += __shfl_xor(S, 2);
        S += __shfl_xor(S, 4);
        float invS = __builtin_amdgcn_rcpf(S);

        #pragma unroll
        for (int qq = 0; qq < 4; ++qq) {
            float4 a4 = make_float4(pm[4 * qq + 0] * invS, pm[4 * qq + 1] * invS,
                                    pm[4 * qq + 2] * invS, pm[4 * qq + 3] * invS);
            *reinterpret_cast<float4*>(&lb[i][c0 + 32 * qq]) = a4;
        }
        // alpha row i written/read by same 8-lane group (same wave) -> no barrier

        float4 accy = make_float4(0.0f, 0.0f, 0.0f, 0.0f);
        const float* arow = &lb[i][0];
        #pragma unroll 4
        for (int q2 = 0; q2 < 32; ++q2) {
            float4 a4 = *reinterpret_cast<const float4*>(arow + 4 * q2);
            float4 v0 = *reinterpret_cast<const float4*>(&vL[4 * q2 + 0][c0]);
            float4 v1 = *reinterpret_cast<const float4*>(&vL[4 * q2 + 1][c0]);
            float4 v2 = *reinterpret_cast<const float4*>(&vL[4 * q2 + 2][c0]);
            float4 v3 = *reinterpret_cast<const float4*>(&vL[4 * q2 + 3][c0]);
            accy.x += a4.x * v0.x + a4.y * v1.x + a4.z * v2.x + a4.w * v3.x;
            accy.y += a4.x * v0.y + a4.y * v1.y + a4.z * v2.y + a4.w * v3.y;
            accy.z += a4.x * v0.z + a4.y * v1.z + a4.z * v2.z + a4.w * v3.z;
            accy.w += a4.x * v0.w + a4.y * v1.w + a4.z * v2.w + a4.w * v3.w;
        }
        *reinterpret_cast<float4*>(&y[(size_t)b * NN * DD + (size_t)i * DD + h * HD + c0]) = accy;
    }
}

// ---------------- K6: fused FFN + residual + layernorm (Zs overlays As; 80KB -> 2 blk/CU) ----------------
// After GEMM1, As row 2ty+i is read only by its owning half-wave -> in-wave program
// order makes the Zs overlay safe with no extra barrier.
__global__ __launch_bounds__(512) void k_ffn_ln(
    const float* __restrict__ yv, const float* __restrict__ w1,
    const float* __restrict__ b1, const float* __restrict__ w2,
    const float* __restrict__ b2, const float* __restrict__ local,
    const float* __restrict__ g, const float* __restrict__ bb,
    float* __restrict__ out)
{
    __shared__ __align__(16) float Bs[128][128];
    __shared__ __align__(16) float As[32][128];    // y tile; z overlay after GEMM1
    const int mt = blockIdx.x;
    const int b  = mt >> 2;
    const int i0 = (mt & 3) * 32;
    const int tid = threadIdx.x;

    #pragma unroll
    for (int p = 0; p < 8; ++p) {
        int idx = tid + 512 * p;
        int d = idx >> 5, cq = idx & 31;
        *reinterpret_cast<float4*>(&Bs[d][4 * cq]) =
            *reinterpret_cast<const float4*>(&w1[d * FFN_ + 4 * cq]);
    }
    #pragma unroll
    for (int p = 0; p < 2; ++p) {
        int idx = tid + 512 * p;
        int row = idx >> 5, kq = idx & 31;
        *reinterpret_cast<float4*>(&As[row][4 * kq]) =
            *reinterpret_cast<const float4*>(&yv[(size_t)b * NN * DD + (size_t)(i0 + row) * DD + 4 * kq]);
    }
    __syncthreads();

    const int tx = tid & 31, ty = tid >> 5;
    const int c0 = 4 * tx;

    {
        float4 bias = *reinterpret_cast<const float4*>(&b1[c0]);
        float acc[2][4];
        #pragma unroll
        for (int i = 0; i < 2; ++i)
            #pragma unroll
            for (int j = 0; j < 4; ++j) acc[i][j] = 0.0f;
        #pragma unroll 2
        for (int kq = 0; kq < 32; ++kq) {
            float4 b0 = *reinterpret_cast<const float4*>(&Bs[4 * kq + 0][c0]);
            float4 b1v = *reinterpret_cast<const float4*>(&Bs[4 * kq + 1][c0]);
            float4 b2v = *reinterpret_cast<const float4*>(&Bs[4 * kq + 2][c0]);
            float4 b3v = *reinterpret_cast<const float4*>(&Bs[4 * kq + 3][c0]);
            #pragma unroll
            for (int i = 0; i < 2; ++i) {
                float4 a = *reinterpret_cast<const float4*>(&As[2 * ty + i][4 * kq]);
                acc[i][0] += a.x * b0.x + a.y * b1v.x + a.z * b2v.x + a.w * b3v.x;
                acc[i][1] += a.x * b0.y + a.y * b1v.y + a.z * b2v.y + a.w * b3v.y;
                acc[i][2] += a.x * b0.z + a.y * b1v.z + a.z * b2v.z + a.w * b3v.z;
                acc[i][3] += a.x * b0.w + a.y * b1v.w + a.z * b2v.w + a.w * b3v.w;
            }
        }
        // z (relu) overlays As rows 2ty, 2ty+1 (own rows; in-wave ordering safe)
        #pragma unroll
        for (int i = 0; i < 2; ++i) {
            *reinterpret_cast<float4*>(&As[2 * ty + i][c0]) =
                make_float4(fmaxf(acc[i][0] + bias.x, 0.0f), fmaxf(acc[i][1] + bias.y, 0.0f),
                            fmaxf(acc[i][2] + bias.z, 0.0f), fmaxf(acc[i][3] + bias.w, 0.0f));
        }
    }
    __syncthreads();   // all Bs(w1) reads complete

    #pragma unroll
    for (int p = 0; p < 8; ++p) {
        int idx = tid + 512 * p;
        int d = idx >> 5, cq = idx & 31;
        *reinterpret_cast<float4*>(&Bs[d][4 * cq]) =
            *reinterpret_cast<const float4*>(&w2[d * DD + 4 * cq]);
    }
    __syncthreads();

    float4 bias = *reinterpret_cast<const float4*>(&b2[c0]);
    float4 g4 = *reinterpret_cast<const float4*>(&g[c0]);
    float4 bb4 = *reinterpret_cast<const float4*>(&bb[c0]);
    float acc[2][4];
    #pragma unroll
    for (int i = 0; i < 2; ++i)
        #pragma unroll
        for (int j = 0; j < 4; ++j) acc[i][j] = 0.0f;
    #pragma unroll 2
    for (int kq = 0; kq < 32; ++kq) {
        float4 b0 = *reinterpret_cast<const float4*>(&Bs[4 * kq + 0][c0]);
        float4 b1v = *reinterpret_cast<const float4*>(&Bs[4 * kq + 1][c0]);
        float4 b2v = *reinterpret_cast<const float4*>(&Bs[4 * kq + 2][c0]);
        float4 b3v = *reinterpret_cast<const float4*>(&Bs[4 * kq + 3][c0]);
        #pragma unroll
        for (int i = 0; i < 2; ++i) {
            float4 a = *reinterpret_cast<const float4*>(&As[2 * ty + i][4 * kq]);
            acc[i][0] += a.x * b0.x + a.y * b1v.x + a.z * b2v.x + a.w * b3v.x;
            acc[i][1] += a.x * b0.y + a.y * b1v.y + a.z * b2v.y + a.w * b3v.y;
            acc[i][2] += a.x * b0.z + a.y * b1v.z + a.z * b2v.z + a.w * b3v.z;
            acc[i][3] += a.x * b0.w + a.y * b1v.w + a.z * b2v.w + a.w * b3v.w;
        }
    }

    #pragma unroll
    for (int i = 0; i < 2; ++i) {
        size_t base = (size_t)b * NN * DD + (size_t)(i0 + 2 * ty + i) * DD + c0;
        float4 l4 = *reinterpret_cast<const float4*>(&local[base]);
        float4 y4 = *reinterpret_cast<const float4*>(&yv[base]);
        float x0 = acc[i][0] + bias.x + l4.x + y4.x;
        float x1 = acc[i][1] + bias.y + l4.y + y4.y;
        float x2 = acc[i][2] + bias.z + l4.z + y4.z;
        float x3 = acc[i][3] + bias.w + l4.w + y4.w;

        float s = (x0 + x1) + (x2 + x3);
        s += __shfl_xor(s, 1); s += __shfl_xor(s, 2); s += __shfl_xor(s, 4);
        s += __shfl_xor(s, 8); s += __shfl_xor(s, 16);
        float mu = s * (1.0f / 128.0f);
        float d0 = x0 - mu, d1 = x1 - mu, d2 = x2 - mu, d3 = x3 - mu;
        float v = (d0 * d0 + d1 * d1) + (d2 * d2 + d3 * d3);
        v += __shfl_xor(v, 1); v += __shfl_xor(v, 2); v += __shfl_xor(v, 4);
        v += __shfl_xor(v, 8); v += __shfl_xor(v, 16);
        float rstd = rsqrtf(v * (1.0f / 128.0f) + 1e-5f);
        float4 o = make_float4(d0 * rstd * g4.x + bb4.x, d1 * rstd * g4.y + bb4.y,
                               d2 * rstd * g4.z + bb4.z, d3 * rstd * g4.w + bb4.w);
        *reinterpret_cast<float4*>(&out[base]) = o;
    }
}

extern "C" void kernel_launch(void* const* d_in, const int* in_sizes, int n_in,
                              void* d_out, int out_size, void* d_ws, size_t ws_size,
                              hipStream_t stream) {
    const float* hidden = (const float*)d_in[0];
    const int*   adj    = (const int*)d_in[1];
    const float* a0 = (const float*)d_in[2];
    const float* a1 = (const float*)d_in[3];
    const float* a2 = (const float*)d_in[4];
    const float* a3 = (const float*)d_in[5];
    const float* wa = (const float*)d_in[6];
    const float* ba = (const float*)d_in[7];
    const float* wq = (const float*)d_in[8];
    const float* bq = (const float*)d_in[9];
    const float* wk = (const float*)d_in[10];
    const float* bk = (const float*)d_in[11];
    const float* wv = (const float*)d_in[12];
    const float* bv = (const float*)d_in[13];
    const float* w1 = (const float*)d_in[14];
    const float* b1 = (const float*)d_in[15];
    const float* w2 = (const float*)d_in[16];
    const float* b2 = (const float*)d_in[17];
    const float* g  = (const float*)d_in[18];
    const float* bb = (const float*)d_in[19];
    const int* seq_mask = (const int*)d_in[20];

    float* ws   = (float*)d_ws;
    float* local = ws;
    float* yv    = ws + 1048576;
    float* aentw = ws + 2 * 1048576;
    float* out   = (float*)d_out;

    k_att_local<<<dim3(256), dim3(512), 0, stream>>>(hidden, adj, a0, a1, a2, a3,
                                                     wa, ba, local, aentw);
    k_qkv_entmax<<<dim3(256), dim3(1024), 0, stream>>>(local, wq, bq, wk, bk, wv, bv,
                                                       aentw, seq_mask, yv);
    k_ffn_ln<<<dim3(256), dim3(512), 0, stream>>>(yv, w1, b1, w2, b2, local, g, bb, out);
}

// Round 18
// 65.646 us; speedup vs baseline: 1.0121x; 1.0121x over previous
//
#include <hip/hip_runtime.h>
#include <math.h>

#define BB 64
#define NN 128
#define DD 128
#define HH 4
#define HD 32
#define FFN_ 128

static constexpr float NEGV  = -9000000000000000.0f;
static constexpr float SLOPE = 0.2f;
static constexpr float SCALE = 0.08838834764831845f; // 1/sqrt(128)
#define NEWTON_ITERS 4

__device__ __forceinline__ float4 f4fma(float s, float4 w, float4 a) {
    a.x += s * w.x; a.y += s * w.y; a.z += s * w.z; a.w += s * w.w; return a;
}

// ---------------- K1: edge attention + softmax + local = att@hidden (+a_ent) ----------------
__global__ __launch_bounds__(512) void k_att_local(
    const float* __restrict__ hidden, const int* __restrict__ adj,
    const float* __restrict__ a0, const float* __restrict__ a1,
    const float* __restrict__ a2, const float* __restrict__ a3,
    const float* __restrict__ wa, const float* __restrict__ ba,
    float* __restrict__ local, float* __restrict__ aent_out)
{
    __shared__ __align__(16) float At[4][132];
    __shared__ __align__(16) float hb[128][128];   // swizzled
    __shared__ __align__(16) float hA[128][132];   // [i*4+r][d], i=0..31 local
    __shared__ __align__(16) float att[32][132];

    const int blk = blockIdx.x;
    const int b  = blk >> 2;
    const int i0 = (blk & 3) * 32;
    const int tid = threadIdx.x;

    {
        int r = tid >> 7, d = tid & 127;
        float v = (r == 0) ? a0[d] : (r == 1) ? a1[d] : (r == 2) ? a2[d] : a3[d];
        At[r][d] = v;
    }
    #pragma unroll
    for (int p = 0; p < 8; ++p) {
        int q = tid + 512 * p;
        int r = q >> 5, cq = q & 31;
        *reinterpret_cast<float4*>(&hb[r][4 * (cq ^ (r >> 2))]) =
            *reinterpret_cast<const float4*>(&hidden[(size_t)b * NN * DD + (size_t)r * DD + 4 * cq]);
    }
    __syncthreads();

    // ---- precompute hA
    #pragma unroll
    for (int p = 0; p < 8; ++p) {
        int idx = tid + 512 * p;
        int i  = idx >> 7;
        int r  = (idx >> 5) & 3;
        int dq = idx & 31;
        float4 hv = *reinterpret_cast<const float4*>(&hb[i0 + i][4 * (dq ^ ((i0 + i) >> 2))]);
        float4 av = *reinterpret_cast<const float4*>(&At[r][4 * dq]);
        *reinterpret_cast<float4*>(&hA[i * 4 + r][4 * dq]) =
            make_float4(hv.x * av.x, hv.y * av.y, hv.z * av.z, hv.w * av.w);
    }
    __syncthreads();

    // ---- Phase A
    {
        const int ig = tid >> 7;
        const int j  = tid & 127;
        const int ib = 8 * ig;
        const int jx = j >> 2;
        int rowk[8];
        bool vk[8];
        #pragma unroll
        for (int k = 0; k < 8; ++k) {
            int a = adj[(size_t)b * NN * NN + (size_t)(i0 + ib + k) * NN + j];
            bool v = (a >= 1 && a <= 4);
            vk[k] = v;
            rowk[k] = (ib + k) * 4 + (v ? (a - 1) : 0);
        }
        float acc[8];
        #pragma unroll
        for (int k = 0; k < 8; ++k) acc[k] = 0.0f;
        #pragma unroll 2
        for (int dq = 0; dq < 32; ++dq) {
            float4 jv = *reinterpret_cast<const float4*>(&hb[j][4 * (dq ^ jx)]);
            #pragma unroll
            for (int k = 0; k < 8; ++k) {
                float4 A = *reinterpret_cast<const float4*>(&hA[rowk[k]][4 * dq]);
                acc[k] += A.x * jv.x + A.y * jv.y + A.z * jv.z + A.w * jv.w;
            }
        }
        #pragma unroll
        for (int k = 0; k < 8; ++k) {
            float e = (acc[k] > 0.0f) ? acc[k] : SLOPE * acc[k];
            att[ib + k][j] = vk[k] ? e : NEGV;
        }
    }
    __syncthreads();

    const int ti2 = tid >> 5;
    const int tl  = tid & 31;

    // ---- Phase B
    #pragma unroll
    for (int rr = 0; rr < 2; ++rr) {
        int row = 2 * ti2 + rr;
        float x0 = att[row][tl], x1 = att[row][tl + 32], x2 = att[row][tl + 64], x3 = att[row][tl + 96];
        float m = fmaxf(fmaxf(x0, x1), fmaxf(x2, x3));
        #pragma unroll
        for (int off = 16; off >= 1; off >>= 1) m = fmaxf(m, __shfl_xor(m, off));
        float q0 = __expf(x0 - m), q1 = __expf(x1 - m), q2 = __expf(x2 - m), q3 = __expf(x3 - m);
        float s = (q0 + q1) + (q2 + q3);
        #pragma unroll
        for (int off = 16; off >= 1; off >>= 1) s += __shfl_xor(s, off);
        float invs = 1.0f / s;
        att[row][tl]      = q0 * invs;
        att[row][tl + 32] = q1 * invs;
        att[row][tl + 64] = q2 * invs;
        att[row][tl + 96] = q3 * invs;
    }

    // ---- Phase C
    const int jg = 4 * tl;
    const int rA = 2 * ti2, rB = 2 * ti2 + 1;
    float4 accA = make_float4(0.0f, 0.0f, 0.0f, 0.0f);
    float4 accB = make_float4(0.0f, 0.0f, 0.0f, 0.0f);
    #pragma unroll 4
    for (int jq = 0; jq < 32; ++jq) {
        int xc = 4 * (tl ^ jq);
        #pragma unroll
        for (int k = 0; k < 4; ++k) {
            int j = 4 * jq + k;
            float aAv = att[rA][j];
            float aBv = att[rB][j];
            float4 h4 = *reinterpret_cast<const float4*>(&hb[j][xc]);
            accA.x += aAv * h4.x; accA.y += aAv * h4.y;
            accA.z += aAv * h4.z; accA.w += aAv * h4.w;
            accB.x += aBv * h4.x; accB.y += aBv * h4.y;
            accB.z += aBv * h4.z; accB.w += aBv * h4.w;
        }
    }
    *reinterpret_cast<float4*>(&local[(size_t)b * NN * DD + (size_t)(i0 + rA) * DD + jg]) = accA;
    *reinterpret_cast<float4*>(&local[(size_t)b * NN * DD + (size_t)(i0 + rB) * DD + jg]) = accB;

    // ---- a_ent
    if (((blk & 3) == 3) && ti2 == 15) {
        float4 wa4 = *reinterpret_cast<const float4*>(&wa[jg]);
        float dp = accB.x * wa4.x + accB.y * wa4.y + accB.z * wa4.z + accB.w * wa4.w;
        #pragma unroll
        for (int off = 16; off >= 1; off >>= 1) dp += __shfl_xor(dp, off, 32);
        if (tl == 0) {
            float z = dp + ba[0];
            float sig = 1.0f / (1.0f + __expf(-z));
            float a = sig + 1.0f;
            if (a == 1.0f) a = 1.00001f;
            aent_out[b] = a;
        }
    }
}

// ---------------- K5: fused QKV (4-row split GEMM) + scores + entmax (2-row, 8 waves) + y ----------------
__global__ __launch_bounds__(1024) void k_qkv_entmax(
    const float* __restrict__ local,
    const float* __restrict__ wq, const float* __restrict__ bq,
    const float* __restrict__ wk, const float* __restrict__ bk,
    const float* __restrict__ wv, const float* __restrict__ bv,
    const float* __restrict__ aent, const int* __restrict__ seq_mask,
    float* __restrict__ y)
{
    __shared__ __align__(16) float lb[128][132];   // local[b]; alpha overlay after GEMM
    __shared__ __align__(16) float wQs[128][36];   // wq slice; Q after overlay
    __shared__ __align__(16) float wKs[128][36];
    __shared__ __align__(16) float wVs[128][36];
    __shared__ __align__(16) float kx[32][132];    // K^T [dh][j]
    __shared__ __align__(16) float vL[128][32];    // V [j][dh]
    __shared__ int maskL[NN];
    __shared__ float aent_sh;

    const int blk = blockIdx.x;
    const int b = blk >> 2, h = blk & 3;
    const int tid = threadIdx.x;

    #pragma unroll
    for (int p = 0; p < 4; ++p) {
        int idx = tid + 1024 * p;
        int r = idx >> 5, cq = idx & 31;
        *reinterpret_cast<float4*>(&lb[r][4 * cq]) =
            *reinterpret_cast<const float4*>(&local[(size_t)b * NN * DD + (size_t)r * DD + 4 * cq]);
    }
    {
        int d = tid >> 3, c4 = 4 * (tid & 7);
        size_t off = (size_t)d * DD + h * HD + c4;
        *reinterpret_cast<float4*>(&wQs[d][c4]) = *reinterpret_cast<const float4*>(&wq[off]);
        *reinterpret_cast<float4*>(&wKs[d][c4]) = *reinterpret_cast<const float4*>(&wk[off]);
        *reinterpret_cast<float4*>(&wVs[d][c4]) = *reinterpret_cast<const float4*>(&wv[off]);
    }
    if (tid < NN) maskL[tid] = seq_mask[b * NN + tid];
    if (tid == 0) aent_sh = aent[b];
    __syncthreads();

    const int t256 = tid & 255;
    const int rp4  = t256 >> 3;
    const int tx4  = t256 & 7;
    const int cg4  = 4 * tx4;
    float4 qa[4];

    if (tid < 256) {
        float4 kb4 = *reinterpret_cast<const float4*>(&bk[h * HD + cg4]);
        float4 vb4 = *reinterpret_cast<const float4*>(&bv[h * HD + cg4]);
        float4 ka0 = kb4, ka1 = kb4, ka2 = kb4, ka3 = kb4;
        float4 va0 = vb4, va1 = vb4, va2 = vb4, va3 = vb4;
        #pragma unroll 4
        for (int kq = 0; kq < 32; ++kq) {
            float4 a0 = *reinterpret_cast<const float4*>(&lb[rp4 +  0][4 * kq]);
            float4 a1 = *reinterpret_cast<const float4*>(&lb[rp4 + 32][4 * kq]);
            float4 a2 = *reinterpret_cast<const float4*>(&lb[rp4 + 64][4 * kq]);
            float4 a3 = *reinterpret_cast<const float4*>(&lb[rp4 + 96][4 * kq]);
            {
                float4 w0 = *reinterpret_cast<const float4*>(&wKs[4 * kq + 0][cg4]);
                float4 w1 = *reinterpret_cast<const float4*>(&wKs[4 * kq + 1][cg4]);
                float4 w2 = *reinterpret_cast<const float4*>(&wKs[4 * kq + 2][cg4]);
                float4 w3 = *reinterpret_cast<const float4*>(&wKs[4 * kq + 3][cg4]);
                ka0 = f4fma(a0.x, w0, ka0); ka0 = f4fma(a0.y, w1, ka0);
                ka0 = f4fma(a0.z, w2, ka0); ka0 = f4fma(a0.w, w3, ka0);
                ka1 = f4fma(a1.x, w0, ka1); ka1 = f4fma(a1.y, w1, ka1);
                ka1 = f4fma(a1.z, w2, ka1); ka1 = f4fma(a1.w, w3, ka1);
                ka2 = f4fma(a2.x, w0, ka2); ka2 = f4fma(a2.y, w1, ka2);
                ka2 = f4fma(a2.z, w2, ka2); ka2 = f4fma(a2.w, w3, ka2);
                ka3 = f4fma(a3.x, w0, ka3); ka3 = f4fma(a3.y, w1, ka3);
                ka3 = f4fma(a3.z, w2, ka3); ka3 = f4fma(a3.w, w3, ka3);
            }
            {
                float4 w0 = *reinterpret_cast<const float4*>(&wVs[4 * kq + 0][cg4]);
                float4 w1 = *reinterpret_cast<const float4*>(&wVs[4 * kq + 1][cg4]);
                float4 w2 = *reinterpret_cast<const float4*>(&wVs[4 * kq + 2][cg4]);
                float4 w3 = *reinterpret_cast<const float4*>(&wVs[4 * kq + 3][cg4]);
                va0 = f4fma(a0.x, w0, va0); va0 = f4fma(a0.y, w1, va0);
                va0 = f4fma(a0.z, w2, va0); va0 = f4fma(a0.w, w3, va0);
                va1 = f4fma(a1.x, w0, va1); va1 = f4fma(a1.y, w1, va1);
                va1 = f4fma(a1.z, w2, va1); va1 = f4fma(a1.w, w3, va1);
                va2 = f4fma(a2.x, w0, va2); va2 = f4fma(a2.y, w1, va2);
                va2 = f4fma(a2.z, w2, va2); va2 = f4fma(a2.w, w3, va2);
                va3 = f4fma(a3.x, w0, va3); va3 = f4fma(a3.y, w1, va3);
                va3 = f4fma(a3.z, w2, va3); va3 = f4fma(a3.w, w3, va3);
            }
        }
        kx[cg4 + 0][rp4 +  0] = ka0.x; kx[cg4 + 1][rp4 +  0] = ka0.y;
        kx[cg4 + 2][rp4 +  0] = ka0.z; kx[cg4 + 3][rp4 +  0] = ka0.w;
        kx[cg4 + 0][rp4 + 32] = ka1.x; kx[cg4 + 1][rp4 + 32] = ka1.y;
        kx[cg4 + 2][rp4 + 32] = ka1.z; kx[cg4 + 3][rp4 + 32] = ka1.w;
        kx[cg4 + 0][rp4 + 64] = ka2.x; kx[cg4 + 1][rp4 + 64] = ka2.y;
        kx[cg4 + 2][rp4 + 64] = ka2.z; kx[cg4 + 3][rp4 + 64] = ka2.w;
        kx[cg4 + 0][rp4 + 96] = ka3.x; kx[cg4 + 1][rp4 + 96] = ka3.y;
        kx[cg4 + 2][rp4 + 96] = ka3.z; kx[cg4 + 3][rp4 + 96] = ka3.w;
        *reinterpret_cast<float4*>(&vL[rp4 +  0][cg4]) = va0;
        *reinterpret_cast<float4*>(&vL[rp4 + 32][cg4]) = va1;
        *reinterpret_cast<float4*>(&vL[rp4 + 64][cg4]) = va2;
        *reinterpret_cast<float4*>(&vL[rp4 + 96][cg4]) = va3;
    } else if (tid < 512) {
        float4 qb4 = *reinterpret_cast<const float4*>(&bq[h * HD + cg4]);
        qa[0] = qb4; qa[1] = qb4; qa[2] = qb4; qa[3] = qb4;
        #pragma unroll 4
        for (int kq = 0; kq < 32; ++kq) {
            float4 a0 = *reinterpret_cast<const float4*>(&lb[rp4 +  0][4 * kq]);
            float4 a1 = *reinterpret_cast<const float4*>(&lb[rp4 + 32][4 * kq]);
            float4 a2 = *reinterpret_cast<const float4*>(&lb[rp4 + 64][4 * kq]);
            float4 a3 = *reinterpret_cast<const float4*>(&lb[rp4 + 96][4 * kq]);
            float4 w0 = *reinterpret_cast<const float4*>(&wQs[4 * kq + 0][cg4]);
            float4 w1 = *reinterpret_cast<const float4*>(&wQs[4 * kq + 1][cg4]);
            float4 w2 = *reinterpret_cast<const float4*>(&wQs[4 * kq + 2][cg4]);
            float4 w3 = *reinterpret_cast<const float4*>(&wQs[4 * kq + 3][cg4]);
            qa[0] = f4fma(a0.x, w0, qa[0]); qa[0] = f4fma(a0.y, w1, qa[0]);
            qa[0] = f4fma(a0.z, w2, qa[0]); qa[0] = f4fma(a0.w, w3, qa[0]);
            qa[1] = f4fma(a1.x, w0, qa[1]); qa[1] = f4fma(a1.y, w1, qa[1]);
            qa[1] = f4fma(a1.z, w2, qa[1]); qa[1] = f4fma(a1.w, w3, qa[1]);
            qa[2] = f4fma(a2.x, w0, qa[2]); qa[2] = f4fma(a2.y, w1, qa[2]);
            qa[2] = f4fma(a2.z, w2, qa[2]); qa[2] = f4fma(a2.w, w3, qa[2]);
            qa[3] = f4fma(a3.x, w0, qa[3]); qa[3] = f4fma(a3.y, w1, qa[3]);
            qa[3] = f4fma(a3.z, w2, qa[3]); qa[3] = f4fma(a3.w, w3, qa[3]);
        }
    }
    __syncthreads();

    if (tid >= 256 && tid < 512) {
        *reinterpret_cast<float4*>(&wQs[rp4 +  0][cg4]) = qa[0];
        *reinterpret_cast<float4*>(&wQs[rp4 + 32][cg4]) = qa[1];
        *reinterpret_cast<float4*>(&wQs[rp4 + 64][cg4]) = qa[2];
        *reinterpret_cast<float4*>(&wQs[rp4 + 96][cg4]) = qa[3];
    }
    __syncthreads();

    // ================= entmax: threads 0..511, rows rp and rp+64 (R16 proven) =================
    if (tid < 512) {
        const int rp  = tid >> 3;
        const int sub = tid & 7;
        const int c0  = 4 * sub;
        const int iA  = rp, iB = rp + 64;

        const float am1 = aent_sh - 1.0f;
        const float inv = 1.0f / am1;
        const float invm1 = inv - 1.0f;
        const float thi_off = exp2f(-7.0f * am1);
        const float sc = SCALE * am1;
        const float xneg = -1000000000.0f * am1;

        float xvA[16], xvB[16];
        #pragma unroll
        for (int s = 0; s < 16; ++s) { xvA[s] = 0.0f; xvB[s] = 0.0f; }
        #pragma unroll
        for (int dq = 0; dq < 8; ++dq) {
            float4 qA = *reinterpret_cast<const float4*>(&wQs[iA][4 * dq]);
            float4 qB = *reinterpret_cast<const float4*>(&wQs[iB][4 * dq]);
            #pragma unroll
            for (int kk = 0; kk < 4; ++kk) {
                int dh = 4 * dq + kk;
                float qa_ = (kk == 0) ? qA.x : (kk == 1) ? qA.y : (kk == 2) ? qA.z : qA.w;
                float qb_ = (kk == 0) ? qB.x : (kk == 1) ? qB.y : (kk == 2) ? qB.z : qB.w;
                #pragma unroll
                for (int qq = 0; qq < 4; ++qq) {
                    float4 k4 = *reinterpret_cast<const float4*>(&kx[dh][c0 + 32 * qq]);
                    xvA[4 * qq + 0] += qa_ * k4.x;  xvB[4 * qq + 0] += qb_ * k4.x;
                    xvA[4 * qq + 1] += qa_ * k4.y;  xvB[4 * qq + 1] += qb_ * k4.y;
                    xvA[4 * qq + 2] += qa_ * k4.z;  xvB[4 * qq + 2] += qb_ * k4.z;
                    xvA[4 * qq + 3] += qa_ * k4.w;  xvB[4 * qq + 3] += qb_ * k4.w;
                }
            }
        }
        #pragma unroll
        for (int qq = 0; qq < 4; ++qq) {
            int4 m4 = *reinterpret_cast<const int4*>(&maskL[c0 + 32 * qq]);
            xvA[4 * qq + 0] = (m4.x == 0) ? xneg : xvA[4 * qq + 0] * sc;
            xvA[4 * qq + 1] = (m4.y == 0) ? xneg : xvA[4 * qq + 1] * sc;
            xvA[4 * qq + 2] = (m4.z == 0) ? xneg : xvA[4 * qq + 2] * sc;
            xvA[4 * qq + 3] = (m4.w == 0) ? xneg : xvA[4 * qq + 3] * sc;
            xvB[4 * qq + 0] = (m4.x == 0) ? xneg : xvB[4 * qq + 0] * sc;
            xvB[4 * qq + 1] = (m4.y == 0) ? xneg : xvB[4 * qq + 1] * sc;
            xvB[4 * qq + 2] = (m4.z == 0) ? xneg : xvB[4 * qq + 2] * sc;
            xvB[4 * qq + 3] = (m4.w == 0) ? xneg : xvB[4 * qq + 3] * sc;
        }

        float mxA = xvA[0], mxB = xvB[0];
        #pragma unroll
        for (int s = 1; s < 16; ++s) { mxA = fmaxf(mxA, xvA[s]); mxB = fmaxf(mxB, xvB[s]); }
        mxA = fmaxf(mxA, __shfl_xor(mxA, 1)); mxB = fmaxf(mxB, __shfl_xor(mxB, 1));
        mxA = fmaxf(mxA, __shfl_xor(mxA, 2)); mxB = fmaxf(mxB, __shfl_xor(mxB, 2));
        mxA = fmaxf(mxA, __shfl_xor(mxA, 4)); mxB = fmaxf(mxB, __shfl_xor(mxB, 4));

        const float hiA = mxA - thi_off, hiB = mxB - thi_off;
        float tauA = mxA - 1.0f, tauB = mxB - 1.0f;

        #pragma unroll
        for (int it = 0; it < NEWTON_ITERS; ++it) {
            float psA = 0.0f, dsA = 0.0f, psB = 0.0f, dsB = 0.0f;
            #pragma unroll
            for (int s = 0; s < 16; ++s) {
                float tA = fmaxf(xvA[s] - tauA, 0.0f);
                float lA = __builtin_amdgcn_logf(tA);
                float dA = __builtin_amdgcn_exp2f(invm1 * lA);
                float pA = tA * dA;
                psA += pA; dsA += dA;
                float tB = fmaxf(xvB[s] - tauB, 0.0f);
                float lB = __builtin_amdgcn_logf(tB);
                float dB = __builtin_amdgcn_exp2f(invm1 * lB);
                float pB = tB * dB;
                psB += pB; dsB += dB;
            }
            psA += __shfl_xor(psA, 1); dsA += __shfl_xor(dsA, 1);
            psA += __shfl_xor(psA, 2); dsA += __shfl_xor(dsA, 2);
            psA += __shfl_xor(psA, 4); dsA += __shfl_xor(dsA, 4);
            psB += __shfl_xor(psB, 1); dsB += __shfl_xor(dsB, 1);
            psB += __shfl_xor(psB, 2); dsB += __shfl_xor(dsB, 2);
            psB += __shfl_xor(psB, 4); dsB += __shfl_xor(dsB, 4);
            tauA = fminf(tauA + (psA - 1.0f) * __builtin_amdgcn_rcpf(inv * dsA), hiA);
            tauB = fminf(tauB + (psB - 1.0f) * __builtin_amdgcn_rcpf(inv * dsB), hiB);
        }

        {
            float pm[16]; float S = 0.0f;
            #pragma unroll
            for (int s = 0; s < 16; ++s) {
                float t = fmaxf(xvA[s] - tauA, 0.0f);
                float l = __builtin_amdgcn_logf(t);
                float p = t * __builtin_amdgcn_exp2f(invm1 * l);
                pm[s] = p; S += p;
            }
            S += __shfl_xor(S, 1); S += __shfl_xor(S, 2); S += __shfl_xor(S, 4);
            float invS = __builtin_amdgcn_rcpf(S);
            #pragma unroll
            for (int qq = 0; qq < 4; ++qq) {
                float4 a4 = make_float4(pm[4 * qq + 0] * invS, pm[4 * qq + 1] * invS,
                                        pm[4 * qq + 2] * invS, pm[4 * qq + 3] * invS);
                *reinterpret_cast<float4*>(&lb[iA][c0 + 32 * qq]) = a4;
            }
        }
        {
            float pm[16]; float S = 0.0f;
            #pragma unroll
            for (int s = 0; s < 16; ++s) {
                float t = fmaxf(xvB[s] - tauB, 0.0f);
                float l = __builtin_amdgcn_logf(t);
                float p = t * __builtin_amdgcn_exp2f(invm1 * l);
                pm[s] = p; S += p;
            }
            S += __shfl_xor(S, 1); S += __shfl_xor(S, 2); S += __shfl_xor(S, 4);
            float invS = __builtin_amdgcn_rcpf(S);
            #pragma unroll
            for (int qq = 0; qq < 4; ++qq) {
                float4 a4 = make_float4(pm[4 * qq + 0] * invS, pm[4 * qq + 1] * invS,
                                        pm[4 * qq + 2] * invS, pm[4 * qq + 3] * invS);
                *reinterpret_cast<float4*>(&lb[iB][c0 + 32 * qq]) = a4;
            }
        }

        float4 accA = make_float4(0.0f, 0.0f, 0.0f, 0.0f);
        float4 accB = make_float4(0.0f, 0.0f, 0.0f, 0.0f);
        #pragma unroll 4
        for (int q2 = 0; q2 < 32; ++q2) {
            float4 aA = *reinterpret_cast<const float4*>(&lb[iA][4 * q2]);
            float4 aB = *reinterpret_cast<const float4*>(&lb[iB][4 * q2]);
            float4 v0 = *reinterpret_cast<const float4*>(&vL[4 * q2 + 0][c0]);
            float4 v1 = *reinterpret_cast<const float4*>(&vL[4 * q2 + 1][c0]);
            float4 v2 = *reinterpret_cast<const float4*>(&vL[4 * q2 + 2][c0]);
            float4 v3 = *reinterpret_cast<const float4*>(&vL[4 * q2 + 3][c0]);
            accA.x += aA.x * v0.x + aA.y * v1.x + aA.z * v2.x + aA.w * v3.x;
            accA.y += aA.x * v0.y + aA.y * v1.y + aA.z * v2.y + aA.w * v3.y;
            accA.z += aA.x * v0.z + aA.y * v1.z + aA.z * v2.z + aA.w * v3.z;
            accA.w += aA.x * v0.w + aA.y * v1.w + aA.z * v2.w + aA.w * v3.w;
            accB.x += aB.x * v0.x + aB.y * v1.x + aB.z * v2.x + aB.w * v3.x;
            accB.y += aB.x * v0.y + aB.y * v1.y + aB.z * v2.y + aB.w * v3.y;
            accB.z += aB.x * v0.z + aB.y * v1.z + aB.z * v2.z + aB.w * v3.z;
            accB.w += aB.x * v0.w + aB.y * v1.w + aB.z * v2.w + aB.w * v3.w;
        }
        *reinterpret_cast<float4*>(&y[(size_t)b * NN * DD + (size_t)iA * DD + h * HD + c0]) = accA;
        *reinterpret_cast<float4*>(&y[(size_t)b * NN * DD + (size_t)iB * DD + h * HD + c0]) = accB;
    }
}

// ---------------- K6: fused FFN + residual + layernorm (z overlays As; 80KB -> 2 blk/CU) ----------------
__global__ __launch_bounds__(512) void k_ffn_ln(
    const float* __restrict__ yv, const float* __restrict__ w1,
    const float* __restrict__ b1, const float* __restrict__ w2,
    const float* __restrict__ b2, const float* __restrict__ local,
    const float* __restrict__ g, const float* __restrict__ bb,
    float* __restrict__ out)
{
    __shared__ __align__(16) float Bs[128][128];
    __shared__ __align__(16) float As[32][128];    // y tile; z overlay after GEMM1
    const int mt = blockIdx.x;
    const int b  = mt >> 2;
    const int i0 = (mt & 3) * 32;
    const int tid = threadIdx.x;

    #pragma unroll
    for (int p = 0; p < 8; ++p) {
        int idx = tid + 512 * p;
        int d = idx >> 5, cq = idx & 31;
        *reinterpret_cast<float4*>(&Bs[d][4 * cq]) =
            *reinterpret_cast<const float4*>(&w1[d * FFN_ + 4 * cq]);
    }
    #pragma unroll
    for (int p = 0; p < 2; ++p) {
        int idx = tid + 512 * p;
        int row = idx >> 5, kq = idx & 31;
        *reinterpret_cast<float4*>(&As[row][4 * kq]) =
            *reinterpret_cast<const float4*>(&yv[(size_t)b * NN * DD + (size_t)(i0 + row) * DD + 4 * kq]);
    }
    __syncthreads();

    const int tx = tid & 31, ty = tid >> 5;
    const int c0 = 4 * tx;

    {
        float4 bias = *reinterpret_cast<const float4*>(&b1[c0]);
        float acc[2][4];
        #pragma unroll
        for (int i = 0; i < 2; ++i)
            #pragma unroll
            for (int j = 0; j < 4; ++j) acc[i][j] = 0.0f;
        #pragma unroll 2
        for (int kq = 0; kq < 32; ++kq) {
            float4 b0 = *reinterpret_cast<const float4*>(&Bs[4 * kq + 0][c0]);
            float4 b1v = *reinterpret_cast<const float4*>(&Bs[4 * kq + 1][c0]);
            float4 b2v = *reinterpret_cast<const float4*>(&Bs[4 * kq + 2][c0]);
            float4 b3v = *reinterpret_cast<const float4*>(&Bs[4 * kq + 3][c0]);
            #pragma unroll
            for (int i = 0; i < 2; ++i) {
                float4 a = *reinterpret_cast<const float4*>(&As[2 * ty + i][4 * kq]);
                acc[i][0] += a.x * b0.x + a.y * b1v.x + a.z * b2v.x + a.w * b3v.x;
                acc[i][1] += a.x * b0.y + a.y * b1v.y + a.z * b2v.y + a.w * b3v.y;
                acc[i][2] += a.x * b0.z + a.y * b1v.z + a.z * b2v.z + a.w * b3v.z;
                acc[i][3] += a.x * b0.w + a.y * b1v.w + a.z * b2v.w + a.w * b3v.w;
            }
        }
        #pragma unroll
        for (int i = 0; i < 2; ++i) {
            *reinterpret_cast<float4*>(&As[2 * ty + i][c0]) =
                make_float4(fmaxf(acc[i][0] + bias.x, 0.0f), fmaxf(acc[i][1] + bias.y, 0.0f),
                            fmaxf(acc[i][2] + bias.z, 0.0f), fmaxf(acc[i][3] + bias.w, 0.0f));
        }
    }
    __syncthreads();

    #pragma unroll
    for (int p = 0; p < 8; ++p) {
        int idx = tid + 512 * p;
        int d = idx >> 5, cq = idx & 31;
        *reinterpret_cast<float4*>(&Bs[d][4 * cq]) =
            *reinterpret_cast<const float4*>(&w2[d * DD + 4 * cq]);
    }
    __syncthreads();

    float4 bias = *reinterpret_cast<const float4*>(&b2[c0]);
    float4 g4 = *reinterpret_cast<const float4*>(&g[c0]);
    float4 bb4 = *reinterpret_cast<const float4*>(&bb[c0]);
    float acc[2][4];
    #pragma unroll
    for (int i = 0; i < 2; ++i)
        #pragma unroll
        for (int j = 0; j < 4; ++j) acc[i][j] = 0.0f;
    #pragma unroll 2
    for (int kq = 0; kq < 32; ++kq) {
        float4 b0 = *reinterpret_cast<const float4*>(&Bs[4 * kq + 0][c0]);
        float4 b1v = *reinterpret_cast<const float4*>(&Bs[4 * kq + 1][c0]);
        float4 b2v = *reinterpret_cast<const float4*>(&Bs[4 * kq + 2][c0]);
        float4 b3v = *reinterpret_cast<const float4*>(&Bs[4 * kq + 3][c0]);
        #pragma unroll
        for (int i = 0; i < 2; ++i) {
            float4 a = *reinterpret_cast<const float4*>(&As[2 * ty + i][4 * kq]);
            acc[i][0] += a.x * b0.x + a.y * b1v.x + a.z * b2v.x + a.w * b3v.x;
            acc[i][1] += a.x * b0.y + a.y * b1v.y + a.z * b2v.y + a.w * b3v.y;
            acc[i][2] += a.x * b0.z + a.y * b1v.z + a.z * b2v.z + a.w * b3v.z;
            acc[i][3] += a.x * b0.w + a.y * b1v.w + a.z * b2v.w + a.w * b3v.w;
        }
    }

    #pragma unroll
    for (int i = 0; i < 2; ++i) {
        size_t base = (size_t)b * NN * DD + (size_t)(i0 + 2 * ty + i) * DD + c0;
        float4 l4 = *reinterpret_cast<const float4*>(&local[base]);
        float4 y4 = *reinterpret_cast<const float4*>(&yv[base]);
        float x0 = acc[i][0] + bias.x + l4.x + y4.x;
        float x1 = acc[i][1] + bias.y + l4.y + y4.y;
        float x2 = acc[i][2] + bias.z + l4.z + y4.z;
        float x3 = acc[i][3] + bias.w + l4.w + y4.w;

        float s = (x0 + x1) + (x2 + x3);
        s += __shfl_xor(s, 1); s += __shfl_xor(s, 2); s += __shfl_xor(s, 4);
        s += __shfl_xor(s, 8); s += __shfl_xor(s, 16);
        float mu = s * (1.0f / 128.0f);
        float d0 = x0 - mu, d1 = x1 - mu, d2 = x2 - mu, d3 = x3 - mu;
        float v = (d0 * d0 + d1 * d1) + (d2 * d2 + d3 * d3);
        v += __shfl_xor(v, 1); v += __shfl_xor(v, 2); v += __shfl_xor(v, 4);
        v += __shfl_xor(v, 8); v += __shfl_xor(v, 16);
        float rstd = rsqrtf(v * (1.0f / 128.0f) + 1e-5f);
        float4 o = make_float4(d0 * rstd * g4.x + bb4.x, d1 * rstd * g4.y + bb4.y,
                               d2 * rstd * g4.z + bb4.z, d3 * rstd * g4.w + bb4.w);
        *reinterpret_cast<float4*>(&out[base]) = o;
    }
}

extern "C" void kernel_launch(void* const* d_in, const int* in_sizes, int n_in,
                              void* d_out, int out_size, void* d_ws, size_t ws_size,
                              hipStream_t stream) {
    const float* hidden = (const float*)d_in[0];
    const int*   adj    = (const int*)d_in[1];
    const float* a0 = (const float*)d_in[2];
    const float* a1 = (const float*)d_in[3];
    const float* a2 = (const float*)d_in[4];
    const float* a3 = (const float*)d_in[5];
    const float* wa = (const float*)d_in[6];
    const float* ba = (const float*)d_in[7];
    const float* wq = (const float*)d_in[8];
    const float* bq = (const float*)d_in[9];
    const float* wk = (const float*)d_in[10];
    const float* bk = (const float*)d_in[11];
    const float* wv = (const float*)d_in[12];
    const float* bv = (const float*)d_in[13];
    const float* w1 = (const float*)d_in[14];
    const float* b1 = (const float*)d_in[15];
    const float* w2 = (const float*)d_in[16];
    const float* b2 = (const float*)d_in[17];
    const float* g  = (const float*)d_in[18];
    const float* bb = (const float*)d_in[19];
    const int* seq_mask = (const int*)d_in[20];

    float* ws   = (float*)d_ws;
    float* local = ws;
    float* yv    = ws + 1048576;
    float* aentw = ws + 2 * 1048576;
    float* out   = (float*)d_out;

    k_att_local<<<dim3(256), dim3(512), 0, stream>>>(hidden, adj, a0, a1, a2, a3,
                                                     wa, ba, local, aentw);
    k_qkv_entmax<<<dim3(256), dim3(1024), 0, stream>>>(local, wq, bq, wk, bk, wv, bv,
                                                       aentw, seq_mask, yv);
    k_ffn_ln<<<dim3(256), dim3(512), 0, stream>>>(yv, w1, b1, w2, b2, local, g, bb, out);
}

// Round 19
// 65.040 us; speedup vs baseline: 1.0215x; 1.0093x over previous
//
#include <hip/hip_runtime.h>
#include <math.h>

#define BB 64
#define NN 128
#define DD 128
#define HH 4
#define HD 32
#define FFN_ 128

static constexpr float NEGV  = -9000000000000000.0f;
static constexpr float SLOPE = 0.2f;
static constexpr float SCALE = 0.08838834764831845f; // 1/sqrt(128)
#define NEWTON_ITERS 4

__device__ __forceinline__ float4 f4fma(float s, float4 w, float4 a) {
    a.x += s * w.x; a.y += s * w.y; a.z += s * w.z; a.w += s * w.w; return a;
}

// ---------------- K1: edge attention + softmax + local = att@hidden (+a_ent) ----------------
__global__ __launch_bounds__(512) void k_att_local(
    const float* __restrict__ hidden, const int* __restrict__ adj,
    const float* __restrict__ a0, const float* __restrict__ a1,
    const float* __restrict__ a2, const float* __restrict__ a3,
    const float* __restrict__ wa, const float* __restrict__ ba,
    float* __restrict__ local, float* __restrict__ aent_out)
{
    __shared__ __align__(16) float At[4][132];
    __shared__ __align__(16) float hb[128][128];   // swizzled
    __shared__ __align__(16) float hA[128][132];   // [i*4+r][d], i=0..31 local
    __shared__ __align__(16) float att[32][132];

    const int blk = blockIdx.x;
    const int b  = blk >> 2;
    const int i0 = (blk & 3) * 32;
    const int tid = threadIdx.x;

    {
        int r = tid >> 7, d = tid & 127;
        float v = (r == 0) ? a0[d] : (r == 1) ? a1[d] : (r == 2) ? a2[d] : a3[d];
        At[r][d] = v;
    }
    #pragma unroll
    for (int p = 0; p < 8; ++p) {
        int q = tid + 512 * p;
        int r = q >> 5, cq = q & 31;
        *reinterpret_cast<float4*>(&hb[r][4 * (cq ^ (r >> 2))]) =
            *reinterpret_cast<const float4*>(&hidden[(size_t)b * NN * DD + (size_t)r * DD + 4 * cq]);
    }
    __syncthreads();

    // ---- precompute hA
    #pragma unroll
    for (int p = 0; p < 8; ++p) {
        int idx = tid + 512 * p;
        int i  = idx >> 7;
        int r  = (idx >> 5) & 3;
        int dq = idx & 31;
        float4 hv = *reinterpret_cast<const float4*>(&hb[i0 + i][4 * (dq ^ ((i0 + i) >> 2))]);
        float4 av = *reinterpret_cast<const float4*>(&At[r][4 * dq]);
        *reinterpret_cast<float4*>(&hA[i * 4 + r][4 * dq]) =
            make_float4(hv.x * av.x, hv.y * av.y, hv.z * av.z, hv.w * av.w);
    }
    __syncthreads();

    // ---- Phase A
    {
        const int ig = tid >> 7;
        const int j  = tid & 127;
        const int ib = 8 * ig;
        const int jx = j >> 2;
        int rowk[8];
        bool vk[8];
        #pragma unroll
        for (int k = 0; k < 8; ++k) {
            int a = adj[(size_t)b * NN * NN + (size_t)(i0 + ib + k) * NN + j];
            bool v = (a >= 1 && a <= 4);
            vk[k] = v;
            rowk[k] = (ib + k) * 4 + (v ? (a - 1) : 0);
        }
        float acc[8];
        #pragma unroll
        for (int k = 0; k < 8; ++k) acc[k] = 0.0f;
        #pragma unroll 2
        for (int dq = 0; dq < 32; ++dq) {
            float4 jv = *reinterpret_cast<const float4*>(&hb[j][4 * (dq ^ jx)]);
            #pragma unroll
            for (int k = 0; k < 8; ++k) {
                float4 A = *reinterpret_cast<const float4*>(&hA[rowk[k]][4 * dq]);
                acc[k] += A.x * jv.x + A.y * jv.y + A.z * jv.z + A.w * jv.w;
            }
        }
        #pragma unroll
        for (int k = 0; k < 8; ++k) {
            float e = (acc[k] > 0.0f) ? acc[k] : SLOPE * acc[k];
            att[ib + k][j] = vk[k] ? e : NEGV;
        }
    }
    __syncthreads();

    const int ti2 = tid >> 5;
    const int tl  = tid & 31;

    // ---- Phase B
    #pragma unroll
    for (int rr = 0; rr < 2; ++rr) {
        int row = 2 * ti2 + rr;
        float x0 = att[row][tl], x1 = att[row][tl + 32], x2 = att[row][tl + 64], x3 = att[row][tl + 96];
        float m = fmaxf(fmaxf(x0, x1), fmaxf(x2, x3));
        #pragma unroll
        for (int off = 16; off >= 1; off >>= 1) m = fmaxf(m, __shfl_xor(m, off));
        float q0 = __expf(x0 - m), q1 = __expf(x1 - m), q2 = __expf(x2 - m), q3 = __expf(x3 - m);
        float s = (q0 + q1) + (q2 + q3);
        #pragma unroll
        for (int off = 16; off >= 1; off >>= 1) s += __shfl_xor(s, off);
        float invs = 1.0f / s;
        att[row][tl]      = q0 * invs;
        att[row][tl + 32] = q1 * invs;
        att[row][tl + 64] = q2 * invs;
        att[row][tl + 96] = q3 * invs;
    }

    // ---- Phase C
    const int jg = 4 * tl;
    const int rA = 2 * ti2, rB = 2 * ti2 + 1;
    float4 accA = make_float4(0.0f, 0.0f, 0.0f, 0.0f);
    float4 accB = make_float4(0.0f, 0.0f, 0.0f, 0.0f);
    #pragma unroll 4
    for (int jq = 0; jq < 32; ++jq) {
        int xc = 4 * (tl ^ jq);
        #pragma unroll
        for (int k = 0; k < 4; ++k) {
            int j = 4 * jq + k;
            float aAv = att[rA][j];
            float aBv = att[rB][j];
            float4 h4 = *reinterpret_cast<const float4*>(&hb[j][xc]);
            accA.x += aAv * h4.x; accA.y += aAv * h4.y;
            accA.z += aAv * h4.z; accA.w += aAv * h4.w;
            accB.x += aBv * h4.x; accB.y += aBv * h4.y;
            accB.z += aBv * h4.z; accB.w += aBv * h4.w;
        }
    }
    *reinterpret_cast<float4*>(&local[(size_t)b * NN * DD + (size_t)(i0 + rA) * DD + jg]) = accA;
    *reinterpret_cast<float4*>(&local[(size_t)b * NN * DD + (size_t)(i0 + rB) * DD + jg]) = accB;

    // ---- a_ent
    if (((blk & 3) == 3) && ti2 == 15) {
        float4 wa4 = *reinterpret_cast<const float4*>(&wa[jg]);
        float dp = accB.x * wa4.x + accB.y * wa4.y + accB.z * wa4.z + accB.w * wa4.w;
        #pragma unroll
        for (int off = 16; off >= 1; off >>= 1) dp += __shfl_xor(dp, off, 32);
        if (tl == 0) {
            float z = dp + ba[0];
            float sig = 1.0f / (1.0f + __expf(-z));
            float a = sig + 1.0f;
            if (a == 1.0f) a = 1.00001f;
            aent_out[b] = a;
        }
    }
}

// ---------------- K5: fused QKV (ALL-16-wave split GEMM) + scores + entmax (2-row) + y ----------------
// Waves 0-7: K+V for rows rp, rp+64 (rp=tid>>3, 0..63); waves 8-15: Q for the same
// row pair (regs across barrier -> wQs overlay). Row stride 64: 64*132 = 0 mod 32
// -> A-reads bank 4(rp+kq) mod 32, conflict-free. GEMM now has 4 waves/SIMD.
__global__ __launch_bounds__(1024) void k_qkv_entmax(
    const float* __restrict__ local,
    const float* __restrict__ wq, const float* __restrict__ bq,
    const float* __restrict__ wk, const float* __restrict__ bk,
    const float* __restrict__ wv, const float* __restrict__ bv,
    const float* __restrict__ aent, const int* __restrict__ seq_mask,
    float* __restrict__ y)
{
    __shared__ __align__(16) float lb[128][132];   // local[b]; alpha overlay after GEMM
    __shared__ __align__(16) float wQs[128][36];   // wq slice; Q after overlay
    __shared__ __align__(16) float wKs[128][36];
    __shared__ __align__(16) float wVs[128][36];
    __shared__ __align__(16) float kx[32][132];    // K^T [dh][j]
    __shared__ __align__(16) float vL[128][32];    // V [j][dh]
    __shared__ int maskL[NN];
    __shared__ float aent_sh;

    const int blk = blockIdx.x;
    const int b = blk >> 2, h = blk & 3;
    const int tid = threadIdx.x;

    #pragma unroll
    for (int p = 0; p < 4; ++p) {
        int idx = tid + 1024 * p;
        int r = idx >> 5, cq = idx & 31;
        *reinterpret_cast<float4*>(&lb[r][4 * cq]) =
            *reinterpret_cast<const float4*>(&local[(size_t)b * NN * DD + (size_t)r * DD + 4 * cq]);
    }
    {
        int d = tid >> 3, c4 = 4 * (tid & 7);
        size_t off = (size_t)d * DD + h * HD + c4;
        *reinterpret_cast<float4*>(&wQs[d][c4]) = *reinterpret_cast<const float4*>(&wq[off]);
        *reinterpret_cast<float4*>(&wKs[d][c4]) = *reinterpret_cast<const float4*>(&wk[off]);
        *reinterpret_cast<float4*>(&wVs[d][c4]) = *reinterpret_cast<const float4*>(&wv[off]);
    }
    if (tid < NN) maskL[tid] = seq_mask[b * NN + tid];
    if (tid == 0) aent_sh = aent[b];
    __syncthreads();

    const int t512 = tid & 511;
    const int rp   = t512 >> 3;      // 0..63 -> rows rp, rp+64
    const int txg  = t512 & 7;
    const int cg   = 4 * txg;
    const int r0 = rp, r1 = rp + 64;
    float4 qa0, qa1;                 // Q regs live across barrier (waves 8-15)

    if (tid < 512) {
        // K and V, rows rp & rp+64
        float4 kb4 = *reinterpret_cast<const float4*>(&bk[h * HD + cg]);
        float4 vb4 = *reinterpret_cast<const float4*>(&bv[h * HD + cg]);
        float4 ka0 = kb4, ka1 = kb4, va0 = vb4, va1 = vb4;
        #pragma unroll 4
        for (int kq = 0; kq < 32; ++kq) {
            float4 a0 = *reinterpret_cast<const float4*>(&lb[r0][4 * kq]);
            float4 a1 = *reinterpret_cast<const float4*>(&lb[r1][4 * kq]);
            {
                float4 w0 = *reinterpret_cast<const float4*>(&wKs[4 * kq + 0][cg]);
                float4 w1 = *reinterpret_cast<const float4*>(&wKs[4 * kq + 1][cg]);
                float4 w2 = *reinterpret_cast<const float4*>(&wKs[4 * kq + 2][cg]);
                float4 w3 = *reinterpret_cast<const float4*>(&wKs[4 * kq + 3][cg]);
                ka0 = f4fma(a0.x, w0, ka0); ka0 = f4fma(a0.y, w1, ka0);
                ka0 = f4fma(a0.z, w2, ka0); ka0 = f4fma(a0.w, w3, ka0);
                ka1 = f4fma(a1.x, w0, ka1); ka1 = f4fma(a1.y, w1, ka1);
                ka1 = f4fma(a1.z, w2, ka1); ka1 = f4fma(a1.w, w3, ka1);
            }
            {
                float4 w0 = *reinterpret_cast<const float4*>(&wVs[4 * kq + 0][cg]);
                float4 w1 = *reinterpret_cast<const float4*>(&wVs[4 * kq + 1][cg]);
                float4 w2 = *reinterpret_cast<const float4*>(&wVs[4 * kq + 2][cg]);
                float4 w3 = *reinterpret_cast<const float4*>(&wVs[4 * kq + 3][cg]);
                va0 = f4fma(a0.x, w0, va0); va0 = f4fma(a0.y, w1, va0);
                va0 = f4fma(a0.z, w2, va0); va0 = f4fma(a0.w, w3, va0);
                va1 = f4fma(a1.x, w0, va1); va1 = f4fma(a1.y, w1, va1);
                va1 = f4fma(a1.z, w2, va1); va1 = f4fma(a1.w, w3, va1);
            }
        }
        kx[cg + 0][r0] = ka0.x; kx[cg + 1][r0] = ka0.y;
        kx[cg + 2][r0] = ka0.z; kx[cg + 3][r0] = ka0.w;
        kx[cg + 0][r1] = ka1.x; kx[cg + 1][r1] = ka1.y;
        kx[cg + 2][r1] = ka1.z; kx[cg + 3][r1] = ka1.w;
        *reinterpret_cast<float4*>(&vL[r0][cg]) = va0;
        *reinterpret_cast<float4*>(&vL[r1][cg]) = va1;
    } else {
        // Q, rows rp & rp+64
        float4 qb4 = *reinterpret_cast<const float4*>(&bq[h * HD + cg]);
        qa0 = qb4; qa1 = qb4;
        #pragma unroll 4
        for (int kq = 0; kq < 32; ++kq) {
            float4 a0 = *reinterpret_cast<const float4*>(&lb[r0][4 * kq]);
            float4 a1 = *reinterpret_cast<const float4*>(&lb[r1][4 * kq]);
            float4 w0 = *reinterpret_cast<const float4*>(&wQs[4 * kq + 0][cg]);
            float4 w1 = *reinterpret_cast<const float4*>(&wQs[4 * kq + 1][cg]);
            float4 w2 = *reinterpret_cast<const float4*>(&wQs[4 * kq + 2][cg]);
            float4 w3 = *reinterpret_cast<const float4*>(&wQs[4 * kq + 3][cg]);
            qa0 = f4fma(a0.x, w0, qa0); qa0 = f4fma(a0.y, w1, qa0);
            qa0 = f4fma(a0.z, w2, qa0); qa0 = f4fma(a0.w, w3, qa0);
            qa1 = f4fma(a1.x, w0, qa1); qa1 = f4fma(a1.y, w1, qa1);
            qa1 = f4fma(a1.z, w2, qa1); qa1 = f4fma(a1.w, w3, qa1);
        }
    }
    __syncthreads();   // all wQs/wKs/wVs reads complete; kx, vL written

    if (tid >= 512) {  // overlay Q into dead wQs
        *reinterpret_cast<float4*>(&wQs[r0][cg]) = qa0;
        *reinterpret_cast<float4*>(&wQs[r1][cg]) = qa1;
    }
    __syncthreads();   // Q visible

    // ================= entmax: threads 0..511, rows rp and rp+64 (R16 proven) =================
    if (tid < 512) {
        const int sub = t512 & 7;
        const int c0  = 4 * sub;
        const int iA  = rp, iB = rp + 64;

        const float am1 = aent_sh - 1.0f;
        const float inv = 1.0f / am1;
        const float invm1 = inv - 1.0f;
        const float thi_off = exp2f(-7.0f * am1);
        const float sc = SCALE * am1;
        const float xneg = -1000000000.0f * am1;

        float xvA[16], xvB[16];
        #pragma unroll
        for (int s = 0; s < 16; ++s) { xvA[s] = 0.0f; xvB[s] = 0.0f; }
        #pragma unroll
        for (int dq = 0; dq < 8; ++dq) {
            float4 qA = *reinterpret_cast<const float4*>(&wQs[iA][4 * dq]);
            float4 qB = *reinterpret_cast<const float4*>(&wQs[iB][4 * dq]);
            #pragma unroll
            for (int kk = 0; kk < 4; ++kk) {
                int dh = 4 * dq + kk;
                float qa_ = (kk == 0) ? qA.x : (kk == 1) ? qA.y : (kk == 2) ? qA.z : qA.w;
                float qb_ = (kk == 0) ? qB.x : (kk == 1) ? qB.y : (kk == 2) ? qB.z : qB.w;
                #pragma unroll
                for (int qq = 0; qq < 4; ++qq) {
                    float4 k4 = *reinterpret_cast<const float4*>(&kx[dh][c0 + 32 * qq]);
                    xvA[4 * qq + 0] += qa_ * k4.x;  xvB[4 * qq + 0] += qb_ * k4.x;
                    xvA[4 * qq + 1] += qa_ * k4.y;  xvB[4 * qq + 1] += qb_ * k4.y;
                    xvA[4 * qq + 2] += qa_ * k4.z;  xvB[4 * qq + 2] += qb_ * k4.z;
                    xvA[4 * qq + 3] += qa_ * k4.w;  xvB[4 * qq + 3] += qb_ * k4.w;
                }
            }
        }
        #pragma unroll
        for (int qq = 0; qq < 4; ++qq) {
            int4 m4 = *reinterpret_cast<const int4*>(&maskL[c0 + 32 * qq]);
            xvA[4 * qq + 0] = (m4.x == 0) ? xneg : xvA[4 * qq + 0] * sc;
            xvA[4 * qq + 1] = (m4.y == 0) ? xneg : xvA[4 * qq + 1] * sc;
            xvA[4 * qq + 2] = (m4.z == 0) ? xneg : xvA[4 * qq + 2] * sc;
            xvA[4 * qq + 3] = (m4.w == 0) ? xneg : xvA[4 * qq + 3] * sc;
            xvB[4 * qq + 0] = (m4.x == 0) ? xneg : xvB[4 * qq + 0] * sc;
            xvB[4 * qq + 1] = (m4.y == 0) ? xneg : xvB[4 * qq + 1] * sc;
            xvB[4 * qq + 2] = (m4.z == 0) ? xneg : xvB[4 * qq + 2] * sc;
            xvB[4 * qq + 3] = (m4.w == 0) ? xneg : xvB[4 * qq + 3] * sc;
        }

        float mxA = xvA[0], mxB = xvB[0];
        #pragma unroll
        for (int s = 1; s < 16; ++s) { mxA = fmaxf(mxA, xvA[s]); mxB = fmaxf(mxB, xvB[s]); }
        mxA = fmaxf(mxA, __shfl_xor(mxA, 1)); mxB = fmaxf(mxB, __shfl_xor(mxB, 1));
        mxA = fmaxf(mxA, __shfl_xor(mxA, 2)); mxB = fmaxf(mxB, __shfl_xor(mxB, 2));
        mxA = fmaxf(mxA, __shfl_xor(mxA, 4)); mxB = fmaxf(mxB, __shfl_xor(mxB, 4));

        const float hiA = mxA - thi_off, hiB = mxB - thi_off;
        float tauA = mxA - 1.0f, tauB = mxB - 1.0f;

        #pragma unroll
        for (int it = 0; it < NEWTON_ITERS; ++it) {
            float psA = 0.0f, dsA = 0.0f, psB = 0.0f, dsB = 0.0f;
            #pragma unroll
            for (int s = 0; s < 16; ++s) {
                float tA = fmaxf(xvA[s] - tauA, 0.0f);
                float lA = __builtin_amdgcn_logf(tA);
                float dA = __builtin_amdgcn_exp2f(invm1 * lA);
                float pA = tA * dA;
                psA += pA; dsA += dA;
                float tB = fmaxf(xvB[s] - tauB, 0.0f);
                float lB = __builtin_amdgcn_logf(tB);
                float dB = __builtin_amdgcn_exp2f(invm1 * lB);
                float pB = tB * dB;
                psB += pB; dsB += dB;
            }
            psA += __shfl_xor(psA, 1); dsA += __shfl_xor(dsA, 1);
            psA += __shfl_xor(psA, 2); dsA += __shfl_xor(dsA, 2);
            psA += __shfl_xor(psA, 4); dsA += __shfl_xor(dsA, 4);
            psB += __shfl_xor(psB, 1); dsB += __shfl_xor(dsB, 1);
            psB += __shfl_xor(psB, 2); dsB += __shfl_xor(dsB, 2);
            psB += __shfl_xor(psB, 4); dsB += __shfl_xor(dsB, 4);
            tauA = fminf(tauA + (psA - 1.0f) * __builtin_amdgcn_rcpf(inv * dsA), hiA);
            tauB = fminf(tauB + (psB - 1.0f) * __builtin_amdgcn_rcpf(inv * dsB), hiB);
        }

        {
            float pm[16]; float S = 0.0f;
            #pragma unroll
            for (int s = 0; s < 16; ++s) {
                float t = fmaxf(xvA[s] - tauA, 0.0f);
                float l = __builtin_amdgcn_logf(t);
                float p = t * __builtin_amdgcn_exp2f(invm1 * l);
                pm[s] = p; S += p;
            }
            S += __shfl_xor(S, 1); S += __shfl_xor(S, 2); S += __shfl_xor(S, 4);
            float invS = __builtin_amdgcn_rcpf(S);
            #pragma unroll
            for (int qq = 0; qq < 4; ++qq) {
                float4 a4 = make_float4(pm[4 * qq + 0] * invS, pm[4 * qq + 1] * invS,
                                        pm[4 * qq + 2] * invS, pm[4 * qq + 3] * invS);
                *reinterpret_cast<float4*>(&lb[iA][c0 + 32 * qq]) = a4;
            }
        }
        {
            float pm[16]; float S = 0.0f;
            #pragma unroll
            for (int s = 0; s < 16; ++s) {
                float t = fmaxf(xvB[s] - tauB, 0.0f);
                float l = __builtin_amdgcn_logf(t);
                float p = t * __builtin_amdgcn_exp2f(invm1 * l);
                pm[s] = p; S += p;
            }
            S += __shfl_xor(S, 1); S += __shfl_xor(S, 2); S += __shfl_xor(S, 4);
            float invS = __builtin_amdgcn_rcpf(S);
            #pragma unroll
            for (int qq = 0; qq < 4; ++qq) {
                float4 a4 = make_float4(pm[4 * qq + 0] * invS, pm[4 * qq + 1] * invS,
                                        pm[4 * qq + 2] * invS, pm[4 * qq + 3] * invS);
                *reinterpret_cast<float4*>(&lb[iB][c0 + 32 * qq]) = a4;
            }
        }

        float4 accA = make_float4(0.0f, 0.0f, 0.0f, 0.0f);
        float4 accB = make_float4(0.0f, 0.0f, 0.0f, 0.0f);
        #pragma unroll 4
        for (int q2 = 0; q2 < 32; ++q2) {
            float4 aA = *reinterpret_cast<const float4*>(&lb[iA][4 * q2]);
            float4 aB = *reinterpret_cast<const float4*>(&lb[iB][4 * q2]);
            float4 v0 = *reinterpret_cast<const float4*>(&vL[4 * q2 + 0][c0]);
            float4 v1 = *reinterpret_cast<const float4*>(&vL[4 * q2 + 1][c0]);
            float4 v2 = *reinterpret_cast<const float4*>(&vL[4 * q2 + 2][c0]);
            float4 v3 = *reinterpret_cast<const float4*>(&vL[4 * q2 + 3][c0]);
            accA.x += aA.x * v0.x + aA.y * v1.x + aA.z * v2.x + aA.w * v3.x;
            accA.y += aA.x * v0.y + aA.y * v1.y + aA.z * v2.y + aA.w * v3.y;
            accA.z += aA.x * v0.z + aA.y * v1.z + aA.z * v2.z + aA.w * v3.z;
            accA.w += aA.x * v0.w + aA.y * v1.w + aA.z * v2.w + aA.w * v3.w;
            accB.x += aB.x * v0.x + aB.y * v1.x + aB.z * v2.x + aB.w * v3.x;
            accB.y += aB.x * v0.y + aB.y * v1.y + aB.z * v2.y + aB.w * v3.y;
            accB.z += aB.x * v0.z + aB.y * v1.z + aB.z * v2.z + aB.w * v3.z;
            accB.w += aB.x * v0.w + aB.y * v1.w + aB.z * v2.w + aB.w * v3.w;
        }
        *reinterpret_cast<float4*>(&y[(size_t)b * NN * DD + (size_t)iA * DD + h * HD + c0]) = accA;
        *reinterpret_cast<float4*>(&y[(size_t)b * NN * DD + (size_t)iB * DD + h * HD + c0]) = accB;
    }
}

// ---------------- K6: fused FFN + residual + layernorm (z overlays As; 80KB -> 2 blk/CU) ----------------
__global__ __launch_bounds__(512) void k_ffn_ln(
    const float* __restrict__ yv, const float* __restrict__ w1,
    const float* __restrict__ b1, const float* __restrict__ w2,
    const float* __restrict__ b2, const float* __restrict__ local,
    const float* __restrict__ g, const float* __restrict__ bb,
    float* __restrict__ out)
{
    __shared__ __align__(16) float Bs[128][128];
    __shared__ __align__(16) float As[32][128];    // y tile; z overlay after GEMM1
    const int mt = blockIdx.x;
    const int b  = mt >> 2;
    const int i0 = (mt & 3) * 32;
    const int tid = threadIdx.x;

    #pragma unroll
    for (int p = 0; p < 8; ++p) {
        int idx = tid + 512 * p;
        int d = idx >> 5, cq = idx & 31;
        *reinterpret_cast<float4*>(&Bs[d][4 * cq]) =
            *reinterpret_cast<const float4*>(&w1[d * FFN_ + 4 * cq]);
    }
    #pragma unroll
    for (int p = 0; p < 2; ++p) {
        int idx = tid + 512 * p;
        int row = idx >> 5, kq = idx & 31;
        *reinterpret_cast<float4*>(&As[row][4 * kq]) =
            *reinterpret_cast<const float4*>(&yv[(size_t)b * NN * DD + (size_t)(i0 + row) * DD + 4 * kq]);
    }
    __syncthreads();

    const int tx = tid & 31, ty = tid >> 5;
    const int c0 = 4 * tx;

    {
        float4 bias = *reinterpret_cast<const float4*>(&b1[c0]);
        float acc[2][4];
        #pragma unroll
        for (int i = 0; i < 2; ++i)
            #pragma unroll
            for (int j = 0; j < 4; ++j) acc[i][j] = 0.0f;
        #pragma unroll 2
        for (int kq = 0; kq < 32; ++kq) {
            float4 b0 = *reinterpret_cast<const float4*>(&Bs[4 * kq + 0][c0]);
            float4 b1v = *reinterpret_cast<const float4*>(&Bs[4 * kq + 1][c0]);
            float4 b2v = *reinterpret_cast<const float4*>(&Bs[4 * kq + 2][c0]);
            float4 b3v = *reinterpret_cast<const float4*>(&Bs[4 * kq + 3][c0]);
            #pragma unroll
            for (int i = 0; i < 2; ++i) {
                float4 a = *reinterpret_cast<const float4*>(&As[2 * ty + i][4 * kq]);
                acc[i][0] += a.x * b0.x + a.y * b1v.x + a.z * b2v.x + a.w * b3v.x;
                acc[i][1] += a.x * b0.y + a.y * b1v.y + a.z * b2v.y + a.w * b3v.y;
                acc[i][2] += a.x * b0.z + a.y * b1v.z + a.z * b2v.z + a.w * b3v.z;
                acc[i][3] += a.x * b0.w + a.y * b1v.w + a.z * b2v.w + a.w * b3v.w;
            }
        }
        #pragma unroll
        for (int i = 0; i < 2; ++i) {
            *reinterpret_cast<float4*>(&As[2 * ty + i][c0]) =
                make_float4(fmaxf(acc[i][0] + bias.x, 0.0f), fmaxf(acc[i][1] + bias.y, 0.0f),
                            fmaxf(acc[i][2] + bias.z, 0.0f), fmaxf(acc[i][3] + bias.w, 0.0f));
        }
    }
    __syncthreads();

    #pragma unroll
    for (int p = 0; p < 8; ++p) {
        int idx = tid + 512 * p;
        int d = idx >> 5, cq = idx & 31;
        *reinterpret_cast<float4*>(&Bs[d][4 * cq]) =
            *reinterpret_cast<const float4*>(&w2[d * DD + 4 * cq]);
    }
    __syncthreads();

    float4 bias = *reinterpret_cast<const float4*>(&b2[c0]);
    float4 g4 = *reinterpret_cast<const float4*>(&g[c0]);
    float4 bb4 = *reinterpret_cast<const float4*>(&bb[c0]);
    float acc[2][4];
    #pragma unroll
    for (int i = 0; i < 2; ++i)
        #pragma unroll
        for (int j = 0; j < 4; ++j) acc[i][j] = 0.0f;
    #pragma unroll 2
    for (int kq = 0; kq < 32; ++kq) {
        float4 b0 = *reinterpret_cast<const float4*>(&Bs[4 * kq + 0][c0]);
        float4 b1v = *reinterpret_cast<const float4*>(&Bs[4 * kq + 1][c0]);
        float4 b2v = *reinterpret_cast<const float4*>(&Bs[4 * kq + 2][c0]);
        float4 b3v = *reinterpret_cast<const float4*>(&Bs[4 * kq + 3][c0]);
        #pragma unroll
        for (int i = 0; i < 2; ++i) {
            float4 a = *reinterpret_cast<const float4*>(&As[2 * ty + i][4 * kq]);
            acc[i][0] += a.x * b0.x + a.y * b1v.x + a.z * b2v.x + a.w * b3v.x;
            acc[i][1] += a.x * b0.y + a.y * b1v.y + a.z * b2v.y + a.w * b3v.y;
            acc[i][2] += a.x * b0.z + a.y * b1v.z + a.z * b2v.z + a.w * b3v.z;
            acc[i][3] += a.x * b0.w + a.y * b1v.w + a.z * b2v.w + a.w * b3v.w;
        }
    }

    #pragma unroll
    for (int i = 0; i < 2; ++i) {
        size_t base = (size_t)b * NN * DD + (size_t)(i0 + 2 * ty + i) * DD + c0;
        float4 l4 = *reinterpret_cast<const float4*>(&local[base]);
        float4 y4 = *reinterpret_cast<const float4*>(&yv[base]);
        float x0 = acc[i][0] + bias.x + l4.x + y4.x;
        float x1 = acc[i][1] + bias.y + l4.y + y4.y;
        float x2 = acc[i][2] + bias.z + l4.z + y4.z;
        float x3 = acc[i][3] + bias.w + l4.w + y4.w;

        float s = (x0 + x1) + (x2 + x3);
        s += __shfl_xor(s, 1); s += __shfl_xor(s, 2); s += __shfl_xor(s, 4);
        s += __shfl_xor(s, 8); s += __shfl_xor(s, 16);
        float mu = s * (1.0f / 128.0f);
        float d0 = x0 - mu, d1 = x1 - mu, d2 = x2 - mu, d3 = x3 - mu;
        float v = (d0 * d0 + d1 * d1) + (d2 * d2 + d3 * d3);
        v += __shfl_xor(v, 1); v += __shfl_xor(v, 2); v += __shfl_xor(v, 4);
        v += __shfl_xor(v, 8); v += __shfl_xor(v, 16);
        float rstd = rsqrtf(v * (1.0f / 128.0f) + 1e-5f);
        float4 o = make_float4(d0 * rstd * g4.x + bb4.x, d1 * rstd * g4.y + bb4.y,
                               d2 * rstd * g4.z + bb4.z, d3 * rstd * g4.w + bb4.w);
        *reinterpret_cast<float4*>(&out[base]) = o;
    }
}

extern "C" void kernel_launch(void* const* d_in, const int* in_sizes, int n_in,
                              void* d_out, int out_size, void* d_ws, size_t ws_size,
                              hipStream_t stream) {
    const float* hidden = (const float*)d_in[0];
    const int*   adj    = (const int*)d_in[1];
    const float* a0 = (const float*)d_in[2];
    const float* a1 = (const float*)d_in[3];
    const float* a2 = (const float*)d_in[4];
    const float* a3 = (const float*)d_in[5];
    const float* wa = (const float*)d_in[6];
    const float* ba = (const float*)d_in[7];
    const float* wq = (const float*)d_in[8];
    const float* bq = (const float*)d_in[9];
    const float* wk = (const float*)d_in[10];
    const float* bk = (const float*)d_in[11];
    const float* wv = (const float*)d_in[12];
    const float* bv = (const float*)d_in[13];
    const float* w1 = (const float*)d_in[14];
    const float* b1 = (const float*)d_in[15];
    const float* w2 = (const float*)d_in[16];
    const float* b2 = (const float*)d_in[17];
    const float* g  = (const float*)d_in[18];
    const float* bb = (const float*)d_in[19];
    const int* seq_mask = (const int*)d_in[20];

    float* ws   = (float*)d_ws;
    float* local = ws;
    float* yv    = ws + 1048576;
    float* aentw = ws + 2 * 1048576;
    float* out   = (float*)d_out;

    k_att_local<<<dim3(256), dim3(512), 0, stream>>>(hidden, adj, a0, a1, a2, a3,
                                                     wa, ba, local, aentw);
    k_qkv_entmax<<<dim3(256), dim3(1024), 0, stream>>>(local, wq, bq, wk, bk, wv, bv,
                                                       aentw, seq_mask, yv);
    k_ffn_ln<<<dim3(256), dim3(512), 0, stream>>>(yv, w1, b1, w2, b2, local, g, bb, out);
}